// Round 1
// baseline (1139.084 us; speedup 1.0000x reference)
//
#include <hip/hip_runtime.h>
#include <hip/hip_bf16.h>
#include <math.h>

typedef unsigned short u16;
typedef __bf16 bf16_t;
typedef bf16_t bf16x8 __attribute__((ext_vector_type(8)));
typedef float f32x4 __attribute__((ext_vector_type(4)));

#define DEVI static __device__ __forceinline__

constexpr int BATCH = 2, SEQ = 2048, HIDDEN = 2048, NH = 16, NKV = 4, HD = 128;
constexpr int GROUPS = NH / NKV;
constexpr float SCALE = 0.08838834764831845f;  // 128^-0.5

DEVI u16 f2bf(float x){
  unsigned u = __float_as_uint(x);
  u += 0x7FFFu + ((u >> 16) & 1u);
  return (u16)(u >> 16);
}
DEVI float bf2f(u16 h){ return __uint_as_float(((unsigned)h) << 16); }

union FragU { uint4 u; bf16x8 b; };
DEVI bf16x8 ldfrag(const u16* p){
  FragU f; f.u = *reinterpret_cast<const uint4*>(p); return f.b;
}
DEVI f32x4 mfma(bf16x8 a, bf16x8 b, f32x4 c){
  return __builtin_amdgcn_mfma_f32_16x16x32_bf16(a, b, c, 0, 0, 0);
}

// ---------------- elementwise split of hidden_states ----------------
__global__ void k_split(const float* __restrict__ in, u16* __restrict__ hi,
                        u16* __restrict__ lo, int n4){
  int i = blockIdx.x * blockDim.x + threadIdx.x;
  if (i >= n4) return;
  float4 v = reinterpret_cast<const float4*>(in)[i];
  ushort4 h, l;
  h.x = f2bf(v.x); l.x = f2bf(v.x - bf2f(h.x));
  h.y = f2bf(v.y); l.y = f2bf(v.y - bf2f(h.y));
  h.z = f2bf(v.z); l.z = f2bf(v.z - bf2f(h.z));
  h.w = f2bf(v.w); l.w = f2bf(v.w - bf2f(h.w));
  reinterpret_cast<ushort4*>(hi)[i] = h;
  reinterpret_cast<ushort4*>(lo)[i] = l;
}

// ---------------- transpose (K,N)->(N,K) + split convert ----------------
template<bool SPLIT>
__global__ void k_wt(const float* __restrict__ W, u16* __restrict__ hi,
                     u16* __restrict__ lo, int K, int N){
  __shared__ float tile[32][33];
  int k0 = blockIdx.x * 32, n0 = blockIdx.y * 32;
  int c = threadIdx.x & 31, r = threadIdx.x >> 5;
#pragma unroll
  for (int rr = 0; rr < 32; rr += 8)
    tile[r + rr][c] = W[(size_t)(k0 + r + rr) * N + n0 + c];
  __syncthreads();
#pragma unroll
  for (int rr = 0; rr < 32; rr += 8){
    int n = n0 + r + rr, k = k0 + c;
    float x = tile[c][r + rr];
    u16 h = f2bf(x);
    hi[(size_t)n * K + k] = h;
    if (SPLIT) lo[(size_t)n * K + k] = f2bf(x - bf2f(h));
  }
}

// ---------------- GEMM: A (M,K) row-major, B (N,K) row-major, C (M,N) f32 ----------------
template<bool SPLIT>
__global__ __launch_bounds__(256, 2) void k_gemm(
    const u16* __restrict__ Ah, const u16* __restrict__ Al,
    const u16* __restrict__ Bh, const u16* __restrict__ Bl,
    float* __restrict__ C, int M, int N, int K){
  constexpr int LDT = 40;  // 32 + 8 pad (keeps 16B align, spreads banks)
  extern __shared__ u16 smem[];
  u16* sAh = smem;
  u16* sBh = sAh + 128 * LDT;
  u16* sAl = sBh + 128 * LDT;
  u16* sBl = sAl + 128 * LDT;
  int tid = threadIdx.x, lane = tid & 63, w = tid >> 6;
  int wm = w >> 1, wn = w & 1;
  int ml = lane & 15, kg = lane >> 4, kl8 = kg * 8;
  int m0 = blockIdx.x * 128, n0 = blockIdx.y * 128;
  f32x4 acc[4][4] = {};
  for (int k0 = 0; k0 < K; k0 += 32){
    __syncthreads();
#pragma unroll
    for (int ch = 0; ch < 2; ++ch){
      int e = (ch * 256 + tid) * 8;
      int r = e >> 5, cc = e & 31;
      *reinterpret_cast<uint4*>(sAh + r * LDT + cc) =
        *reinterpret_cast<const uint4*>(Ah + (size_t)(m0 + r) * K + k0 + cc);
      *reinterpret_cast<uint4*>(sBh + r * LDT + cc) =
        *reinterpret_cast<const uint4*>(Bh + (size_t)(n0 + r) * K + k0 + cc);
      if (SPLIT){
        *reinterpret_cast<uint4*>(sAl + r * LDT + cc) =
          *reinterpret_cast<const uint4*>(Al + (size_t)(m0 + r) * K + k0 + cc);
        *reinterpret_cast<uint4*>(sBl + r * LDT + cc) =
          *reinterpret_cast<const uint4*>(Bl + (size_t)(n0 + r) * K + k0 + cc);
      }
    }
    __syncthreads();
    bf16x8 bh[4], bl[4];
#pragma unroll
    for (int fn = 0; fn < 4; ++fn){
      bh[fn] = ldfrag(sBh + (wn * 64 + fn * 16 + ml) * LDT + kl8);
      if (SPLIT) bl[fn] = ldfrag(sBl + (wn * 64 + fn * 16 + ml) * LDT + kl8);
    }
#pragma unroll
    for (int fm = 0; fm < 4; ++fm){
      bf16x8 ah = ldfrag(sAh + (wm * 64 + fm * 16 + ml) * LDT + kl8);
      bf16x8 al;
      if (SPLIT) al = ldfrag(sAl + (wm * 64 + fm * 16 + ml) * LDT + kl8);
#pragma unroll
      for (int fn = 0; fn < 4; ++fn){
        if (SPLIT){
          acc[fm][fn] = mfma(al, bh[fn], acc[fm][fn]);
          acc[fm][fn] = mfma(ah, bl[fn], acc[fm][fn]);
        }
        acc[fm][fn] = mfma(ah, bh[fn], acc[fm][fn]);
      }
    }
  }
#pragma unroll
  for (int fm = 0; fm < 4; ++fm)
#pragma unroll
    for (int fn = 0; fn < 4; ++fn)
#pragma unroll
      for (int r = 0; r < 4; ++r)
        C[(size_t)(m0 + wm * 64 + fm * 16 + kg * 4 + r) * N +
          n0 + wn * 64 + fn * 16 + ml] = acc[fm][fn][r];
}

// ---------------- RoPE + split + (b,s,h,d)->(b,h,s,d) ----------------
__global__ void k_rope(const float* __restrict__ src, const float* __restrict__ cosb,
                       const float* __restrict__ sinb, u16* __restrict__ dhi,
                       u16* __restrict__ dlo, int nheads){
  int row = blockIdx.x * 4 + (threadIdx.x >> 6);
  int d = threadIdx.x & 63;
  int h = row % nheads;
  int bs = row / nheads;
  int s = bs & (SEQ - 1);
  int b = bs >> 11;
  const float* sp = src + (size_t)row * HD;
  float x1 = sp[d], x2 = sp[d + 64];
  size_t ci = ((size_t)b * SEQ + s) * HD;
  float o1 = x1 * cosb[ci + d] - x2 * sinb[ci + d];
  float o2 = x2 * cosb[ci + d + 64] + x1 * sinb[ci + d + 64];
  size_t di = (((size_t)b * nheads + h) * SEQ + s) * HD;
  u16 h1 = f2bf(o1), h2 = f2bf(o2);
  dhi[di + d] = h1;       dlo[di + d] = f2bf(o1 - bf2f(h1));
  dhi[di + d + 64] = h2;  dlo[di + d + 64] = f2bf(o2 - bf2f(h2));
}

// ---------------- V: (b,s,kv,d) f32 -> (b,kv,d,s) bf16 ----------------
__global__ void k_vt(const float* __restrict__ src, u16* __restrict__ dst){
  __shared__ float tile[32][33];
  int b = blockIdx.z >> 2, kv = blockIdx.z & 3;
  int s0 = blockIdx.x * 32, d0 = blockIdx.y * 32;
  int c = threadIdx.x & 31, r = threadIdx.x >> 5;
#pragma unroll
  for (int rr = 0; rr < 32; rr += 8)
    tile[r + rr][c] = src[(((size_t)b * SEQ + s0 + r + rr) * NKV + kv) * HD + d0 + c];
  __syncthreads();
#pragma unroll
  for (int rr = 0; rr < 32; rr += 8)
    dst[(((size_t)b * NKV + kv) * HD + d0 + r + rr) * SEQ + s0 + c] = f2bf(tile[c][r + rr]);
}

// ---------------- scores: raw scaled QK^T -> weights region, + row m, 1/l ----------------
__global__ __launch_bounds__(256, 2) void k_scores(
    const u16* __restrict__ qh, const u16* __restrict__ ql,
    const u16* __restrict__ kh, const u16* __restrict__ klo,
    float* __restrict__ wraw, float* __restrict__ mrow, float* __restrict__ lrow){
  int qt = gridDim.x - 1 - blockIdx.x;  // big blocks first
  int h = blockIdx.y, b = blockIdx.z;
  int tid = threadIdx.x, lane = tid & 63, w = tid >> 6;
  int wm = w >> 1, wn = w & 1;
  int ml = lane & 15, kg = lane >> 4, kl8 = kg * 8;
  const u16* qbh = qh + ((size_t)b * NH + h) * SEQ * HD;
  const u16* qbl = ql + ((size_t)b * NH + h) * SEQ * HD;
  const u16* kbh = kh + ((size_t)b * NKV + h / GROUPS) * SEQ * HD;
  const u16* kbl = klo + ((size_t)b * NKV + h / GROUPS) * SEQ * HD;
  float* wout = wraw + ((size_t)b * NH + h) * SEQ * SEQ;
  float run_m[4][4], run_l[4][4];
#pragma unroll
  for (int i = 0; i < 4; ++i)
#pragma unroll
    for (int j = 0; j < 4; ++j){ run_m[i][j] = -1e30f; run_l[i][j] = 0.f; }
  for (int kt = 0; kt <= qt; ++kt){
    f32x4 acc[4][4] = {};
#pragma unroll
    for (int ds = 0; ds < 4; ++ds){
      int kk = ds * 32 + kl8;
      bf16x8 bh[4], bl[4];
#pragma unroll
      for (int fn = 0; fn < 4; ++fn){
        size_t off = (size_t)(kt * 128 + wn * 64 + fn * 16 + ml) * HD + kk;
        bh[fn] = ldfrag(kbh + off);
        bl[fn] = ldfrag(kbl + off);
      }
#pragma unroll
      for (int fm = 0; fm < 4; ++fm){
        size_t off = (size_t)(qt * 128 + wm * 64 + fm * 16 + ml) * HD + kk;
        bf16x8 ah = ldfrag(qbh + off);
        bf16x8 al = ldfrag(qbl + off);
#pragma unroll
        for (int fn = 0; fn < 4; ++fn){
          acc[fm][fn] = mfma(al, bh[fn], acc[fm][fn]);
          acc[fm][fn] = mfma(ah, bl[fn], acc[fm][fn]);
          acc[fm][fn] = mfma(ah, bh[fn], acc[fm][fn]);
        }
      }
    }
    bool diag = (kt == qt);
#pragma unroll
    for (int fm = 0; fm < 4; ++fm){
      int rgb = qt * 128 + wm * 64 + fm * 16 + kg * 4;
#pragma unroll
      for (int r = 0; r < 4; ++r){
        int rg = rgb + r;
        float sv[4];
#pragma unroll
        for (int fn = 0; fn < 4; ++fn){
          float s = acc[fm][fn][r] * SCALE;
          int cg = kt * 128 + wn * 64 + fn * 16 + ml;
          wout[(size_t)rg * SEQ + cg] = s;
          if (diag && cg > rg) s = -1e30f;
          sv[fn] = s;
        }
        float tm = fmaxf(fmaxf(sv[0], sv[1]), fmaxf(sv[2], sv[3]));
#pragma unroll
        for (int xm = 1; xm < 16; xm <<= 1) tm = fmaxf(tm, __shfl_xor(tm, xm, 64));
        float nm = fmaxf(run_m[fm][r], tm);
        float ps = __expf(sv[0] - nm) + __expf(sv[1] - nm) +
                   __expf(sv[2] - nm) + __expf(sv[3] - nm);
#pragma unroll
        for (int xm = 1; xm < 16; xm <<= 1) ps += __shfl_xor(ps, xm, 64);
        run_l[fm][r] = run_l[fm][r] * __expf(run_m[fm][r] - nm) + ps;
        run_m[fm][r] = nm;
      }
    }
  }
  __shared__ float sm[2][128], sl[2][128];
  if (ml == 0){
#pragma unroll
    for (int fm = 0; fm < 4; ++fm)
#pragma unroll
      for (int r = 0; r < 4; ++r){
        sm[wn][wm * 64 + fm * 16 + kg * 4 + r] = run_m[fm][r];
        sl[wn][wm * 64 + fm * 16 + kg * 4 + r] = run_l[fm][r];
      }
  }
  __syncthreads();
  if (tid < 128){
    float m0 = sm[0][tid], m1 = sm[1][tid], l0 = sl[0][tid], l1 = sl[1][tid];
    float mm = fmaxf(m0, m1);
    float ll = l0 * __expf(m0 - mm) + l1 * __expf(m1 - mm);
    size_t idx = ((size_t)b * NH + h) * SEQ + qt * 128 + tid;
    mrow[idx] = mm;
    lrow[idx] = 1.0f / ll;
  }
}

// ---------------- weights finalize: in-place exp((s-m))*1/l, zero upper triangle ----------------
__global__ void k_wfin(float* __restrict__ wbuf, const float* __restrict__ mrow,
                       const float* __restrict__ lrow){
  size_t total4 = (size_t)BATCH * NH * SEQ * SEQ / 4;
  size_t stride = (size_t)gridDim.x * blockDim.x;
  for (size_t i = (size_t)blockIdx.x * blockDim.x + threadIdx.x; i < total4; i += stride){
    size_t e = i * 4;
    int k = (int)(e & (SEQ - 1));
    size_t t = e >> 11;
    int q = (int)(t & (SEQ - 1));
    int bh = (int)(t >> 11);
    float* p = wbuf + e;
    float4 v;
    if (k > q){
      v = make_float4(0.f, 0.f, 0.f, 0.f);
    } else {
      v = *reinterpret_cast<const float4*>(p);
      float m = mrow[(size_t)bh * SEQ + q];
      float rl = lrow[(size_t)bh * SEQ + q];
      v.x = (k + 0 <= q) ? __expf(v.x - m) * rl : 0.f;
      v.y = (k + 1 <= q) ? __expf(v.y - m) * rl : 0.f;
      v.z = (k + 2 <= q) ? __expf(v.z - m) * rl : 0.f;
      v.w = (k + 3 <= q) ? __expf(v.w - m) * rl : 0.f;
    }
    *reinterpret_cast<float4*>(p) = v;
  }
}

// ---------------- PV: weights (f32->bf16 on load) x V^T -> Ao bf16 (b,s,h*HD) ----------------
__global__ __launch_bounds__(256, 2) void k_pv(
    const float* __restrict__ wbuf, const u16* __restrict__ vt, u16* __restrict__ ao){
  int qt = gridDim.x - 1 - blockIdx.x;
  int h = blockIdx.y, b = blockIdx.z;
  int tid = threadIdx.x, lane = tid & 63, w = tid >> 6;
  int wm = w >> 1, wn = w & 1;
  int ml = lane & 15, kg = lane >> 4, kl8 = kg * 8;
  const float* wb = wbuf + ((size_t)b * NH + h) * SEQ * SEQ;
  const u16* vb = vt + ((size_t)b * NKV + h / GROUPS) * HD * SEQ;
  f32x4 acc[4][4] = {};
  for (int kt = 0; kt <= qt; ++kt){
#pragma unroll
    for (int ks = 0; ks < 4; ++ks){
      int kk = kt * 128 + ks * 32 + kl8;
      bf16x8 bfr[4];
#pragma unroll
      for (int fn = 0; fn < 4; ++fn)
        bfr[fn] = ldfrag(vb + (size_t)(wn * 64 + fn * 16 + ml) * SEQ + kk);
      bf16x8 af[4];
#pragma unroll
      for (int fm = 0; fm < 4; ++fm){
        const float* ap = wb + (size_t)(qt * 128 + wm * 64 + fm * 16 + ml) * SEQ + kk;
        float4 s0 = *reinterpret_cast<const float4*>(ap);
        float4 s1 = *reinterpret_cast<const float4*>(ap + 4);
        union { bf16x8 v; u16 us[8]; } pk;
        pk.us[0] = f2bf(s0.x); pk.us[1] = f2bf(s0.y); pk.us[2] = f2bf(s0.z); pk.us[3] = f2bf(s0.w);
        pk.us[4] = f2bf(s1.x); pk.us[5] = f2bf(s1.y); pk.us[6] = f2bf(s1.z); pk.us[7] = f2bf(s1.w);
        af[fm] = pk.v;
      }
#pragma unroll
      for (int fm = 0; fm < 4; ++fm)
#pragma unroll
        for (int fn = 0; fn < 4; ++fn)
          acc[fm][fn] = mfma(af[fm], bfr[fn], acc[fm][fn]);
    }
  }
#pragma unroll
  for (int fm = 0; fm < 4; ++fm)
#pragma unroll
    for (int fn = 0; fn < 4; ++fn)
#pragma unroll
      for (int r = 0; r < 4; ++r){
        int crow = wm * 64 + fm * 16 + kg * 4 + r;
        int ccol = wn * 64 + fn * 16 + ml;
        ao[((size_t)b * SEQ + qt * 128 + crow) * (NH * HD) + h * HD + ccol] =
            f2bf(acc[fm][fn][r]);
      }
}

extern "C" void kernel_launch(void* const* d_in, const int* in_sizes, int n_in,
                              void* d_out, int out_size, void* d_ws, size_t ws_size,
                              hipStream_t stream){
  (void)in_sizes; (void)n_in; (void)out_size; (void)ws_size;
  const float* hs   = (const float*)d_in[0];
  const float* cosb = (const float*)d_in[1];
  const float* sinb = (const float*)d_in[2];
  // d_in[3] attention_mask unused: it is exactly the causal mask, applied analytically
  const float* Wq = (const float*)d_in[4];
  const float* Wk = (const float*)d_in[5];
  const float* Wv = (const float*)d_in[6];
  const float* Wo = (const float*)d_in[7];
  float* out  = (float*)d_out;
  float* wmat = out + (size_t)BATCH * SEQ * HIDDEN;  // attn_weights region

  char* ws = (char*)d_ws;
  size_t off = 0;
  auto alloc = [&](size_t bytes)->char*{
    char* p = ws + off; off += (bytes + 255) & ~(size_t)255; return p;
  };
  u16* hs_hi = (u16*)alloc(16777216);
  u16* hs_lo = (u16*)alloc(16777216);
  u16* wq_hi = (u16*)alloc(8388608);
  u16* wq_lo = (u16*)alloc(8388608);
  u16* wk_hi = (u16*)alloc(2097152);
  u16* wk_lo = (u16*)alloc(2097152);
  u16* wv_t  = (u16*)alloc(2097152);
  u16* wo_t  = (u16*)alloc(8388608);
  float* Qraw = (float*)alloc(33554432);
  float* Kraw = (float*)alloc(8388608);
  float* Vraw = (float*)alloc(8388608);
  u16* q_hi = (u16*)alloc(16777216);
  u16* q_lo = (u16*)alloc(16777216);
  u16* k_hi = (u16*)alloc(4194304);
  u16* k_lo = (u16*)alloc(4194304);
  u16* v_t  = (u16*)alloc(4194304);
  float* mrow = (float*)alloc(262144);
  float* lrow = (float*)alloc(262144);
  u16* ao = (u16*)Qraw;  // reuse: Qraw dead after k_rope(Q)

  size_t lds_split = 4 * 128 * 40 * sizeof(u16);
  size_t lds_plain = 2 * 128 * 40 * sizeof(u16);

  k_split<<<8192, 256, 0, stream>>>(hs, hs_hi, hs_lo, BATCH * SEQ * HIDDEN / 4);
  k_wt<true ><<<dim3(64, 64), 256, 0, stream>>>(Wq, wq_hi, wq_lo, HIDDEN, NH * HD);
  k_wt<true ><<<dim3(64, 16), 256, 0, stream>>>(Wk, wk_hi, wk_lo, HIDDEN, NKV * HD);
  k_wt<false><<<dim3(64, 16), 256, 0, stream>>>(Wv, wv_t, nullptr, HIDDEN, NKV * HD);
  k_wt<false><<<dim3(64, 64), 256, 0, stream>>>(Wo, wo_t, nullptr, NH * HD, HIDDEN);

  k_gemm<true ><<<dim3(32, 16), 256, lds_split, stream>>>(hs_hi, hs_lo, wq_hi, wq_lo, Qraw, 4096, 2048, 2048);
  k_gemm<true ><<<dim3(32,  4), 256, lds_split, stream>>>(hs_hi, hs_lo, wk_hi, wk_lo, Kraw, 4096,  512, 2048);
  k_gemm<false><<<dim3(32,  4), 256, lds_plain, stream>>>(hs_hi, nullptr, wv_t, nullptr, Vraw, 4096, 512, 2048);

  k_rope<<<BATCH * SEQ * NH  / 4, 256, 0, stream>>>(Qraw, cosb, sinb, q_hi, q_lo, NH);
  k_rope<<<BATCH * SEQ * NKV / 4, 256, 0, stream>>>(Kraw, cosb, sinb, k_hi, k_lo, NKV);
  k_vt<<<dim3(64, 4, 8), 256, 0, stream>>>(Vraw, v_t);

  k_scores<<<dim3(16, 16, 2), 256, 0, stream>>>(q_hi, q_lo, k_hi, k_lo, wmat, mrow, lrow);
  k_wfin<<<8192, 256, 0, stream>>>(wmat, mrow, lrow);
  k_pv<<<dim3(16, 16, 2), 256, 0, stream>>>(wmat, v_t, ao);

  k_gemm<false><<<dim3(32, 16), 256, lds_plain, stream>>>(ao, nullptr, wo_t, nullptr, out, 4096, 2048, 2048);
}

// Round 2
// 1019.304 us; speedup vs baseline: 1.1175x; 1.1175x over previous
//
#include <hip/hip_runtime.h>
#include <hip/hip_bf16.h>
#include <math.h>

typedef unsigned short u16;
typedef __bf16 bf16_t;
typedef bf16_t bf16x8 __attribute__((ext_vector_type(8)));
typedef float f32x4 __attribute__((ext_vector_type(4)));

#define DEVI static __device__ __forceinline__

constexpr int BATCH = 2, SEQ = 2048, HIDDEN = 2048, NH = 16, NKV = 4, HD = 128;
constexpr int GROUPS = NH / NKV;
constexpr float SCALE = 0.08838834764831845f;  // 128^-0.5

DEVI u16 f2bf(float x){
  unsigned u = __float_as_uint(x);
  u += 0x7FFFu + ((u >> 16) & 1u);
  return (u16)(u >> 16);
}
DEVI float bf2f(u16 h){ return __uint_as_float(((unsigned)h) << 16); }

union FragU { uint4 u; bf16x8 b; };
DEVI bf16x8 ldfrag(const u16* p){
  FragU f; f.u = *reinterpret_cast<const uint4*>(p); return f.b;
}
DEVI f32x4 mfma(bf16x8 a, bf16x8 b, f32x4 c){
  return __builtin_amdgcn_mfma_f32_16x16x32_bf16(a, b, c, 0, 0, 0);
}

// ---------------- elementwise split of hidden_states ----------------
__global__ void k_split(const float* __restrict__ in, u16* __restrict__ hi,
                        u16* __restrict__ lo, int n4){
  int i = blockIdx.x * blockDim.x + threadIdx.x;
  if (i >= n4) return;
  float4 v = reinterpret_cast<const float4*>(in)[i];
  ushort4 h, l;
  h.x = f2bf(v.x); l.x = f2bf(v.x - bf2f(h.x));
  h.y = f2bf(v.y); l.y = f2bf(v.y - bf2f(h.y));
  h.z = f2bf(v.z); l.z = f2bf(v.z - bf2f(h.z));
  h.w = f2bf(v.w); l.w = f2bf(v.w - bf2f(h.w));
  reinterpret_cast<ushort4*>(hi)[i] = h;
  reinterpret_cast<ushort4*>(lo)[i] = l;
}

// ---------------- transpose (K,N)->(N,K) + split convert ----------------
template<bool SPLIT>
__global__ void k_wt(const float* __restrict__ W, u16* __restrict__ hi,
                     u16* __restrict__ lo, int K, int N){
  __shared__ float tile[32][33];
  int k0 = blockIdx.x * 32, n0 = blockIdx.y * 32;
  int c = threadIdx.x & 31, r = threadIdx.x >> 5;
#pragma unroll
  for (int rr = 0; rr < 32; rr += 8)
    tile[r + rr][c] = W[(size_t)(k0 + r + rr) * N + n0 + c];
  __syncthreads();
#pragma unroll
  for (int rr = 0; rr < 32; rr += 8){
    int n = n0 + r + rr, k = k0 + c;
    float x = tile[c][r + rr];
    u16 h = f2bf(x);
    hi[(size_t)n * K + k] = h;
    if (SPLIT) lo[(size_t)n * K + k] = f2bf(x - bf2f(h));
  }
}

// ---------------- GEMM: A (M,K) row-major, B (N,K) row-major, C (M,N) f32 ----------------
template<bool SPLIT>
__global__ __launch_bounds__(256, 2) void k_gemm(
    const u16* __restrict__ Ah, const u16* __restrict__ Al,
    const u16* __restrict__ Bh, const u16* __restrict__ Bl,
    float* __restrict__ C, int M, int N, int K){
  constexpr int LDT = 40;  // 32 + 8 pad
  extern __shared__ u16 smem[];
  u16* sAh = smem;
  u16* sBh = sAh + 128 * LDT;
  u16* sAl = sBh + 128 * LDT;
  u16* sBl = sAl + 128 * LDT;
  int tid = threadIdx.x, lane = tid & 63, w = tid >> 6;
  int wm = w >> 1, wn = w & 1;
  int ml = lane & 15, kg = lane >> 4, kl8 = kg * 8;
  int m0 = blockIdx.x * 128, n0 = blockIdx.y * 128;
  f32x4 acc[4][4] = {};
  for (int k0 = 0; k0 < K; k0 += 32){
    __syncthreads();
#pragma unroll
    for (int ch = 0; ch < 2; ++ch){
      int e = (ch * 256 + tid) * 8;
      int r = e >> 5, cc = e & 31;
      *reinterpret_cast<uint4*>(sAh + r * LDT + cc) =
        *reinterpret_cast<const uint4*>(Ah + (size_t)(m0 + r) * K + k0 + cc);
      *reinterpret_cast<uint4*>(sBh + r * LDT + cc) =
        *reinterpret_cast<const uint4*>(Bh + (size_t)(n0 + r) * K + k0 + cc);
      if (SPLIT){
        *reinterpret_cast<uint4*>(sAl + r * LDT + cc) =
          *reinterpret_cast<const uint4*>(Al + (size_t)(m0 + r) * K + k0 + cc);
        *reinterpret_cast<uint4*>(sBl + r * LDT + cc) =
          *reinterpret_cast<const uint4*>(Bl + (size_t)(n0 + r) * K + k0 + cc);
      }
    }
    __syncthreads();
    bf16x8 bh[4], bl[4];
#pragma unroll
    for (int fn = 0; fn < 4; ++fn){
      bh[fn] = ldfrag(sBh + (wn * 64 + fn * 16 + ml) * LDT + kl8);
      if (SPLIT) bl[fn] = ldfrag(sBl + (wn * 64 + fn * 16 + ml) * LDT + kl8);
    }
#pragma unroll
    for (int fm = 0; fm < 4; ++fm){
      bf16x8 ah = ldfrag(sAh + (wm * 64 + fm * 16 + ml) * LDT + kl8);
      bf16x8 al;
      if (SPLIT) al = ldfrag(sAl + (wm * 64 + fm * 16 + ml) * LDT + kl8);
#pragma unroll
      for (int fn = 0; fn < 4; ++fn){
        if (SPLIT){
          acc[fm][fn] = mfma(al, bh[fn], acc[fm][fn]);
          acc[fm][fn] = mfma(ah, bl[fn], acc[fm][fn]);
        }
        acc[fm][fn] = mfma(ah, bh[fn], acc[fm][fn]);
      }
    }
  }
#pragma unroll
  for (int fm = 0; fm < 4; ++fm)
#pragma unroll
    for (int fn = 0; fn < 4; ++fn)
#pragma unroll
      for (int r = 0; r < 4; ++r)
        C[(size_t)(m0 + wm * 64 + fm * 16 + kg * 4 + r) * N +
          n0 + wn * 64 + fn * 16 + ml] = acc[fm][fn][r];
}

// ---------------- RoPE + split + (b,s,h,d)->(b,h,s,d) ----------------
__global__ void k_rope(const float* __restrict__ src, const float* __restrict__ cosb,
                       const float* __restrict__ sinb, u16* __restrict__ dhi,
                       u16* __restrict__ dlo, int nheads){
  int row = blockIdx.x * 4 + (threadIdx.x >> 6);
  int d = threadIdx.x & 63;
  int h = row % nheads;
  int bs = row / nheads;
  int s = bs & (SEQ - 1);
  int b = bs >> 11;
  const float* sp = src + (size_t)row * HD;
  float x1 = sp[d], x2 = sp[d + 64];
  size_t ci = ((size_t)b * SEQ + s) * HD;
  float o1 = x1 * cosb[ci + d] - x2 * sinb[ci + d];
  float o2 = x2 * cosb[ci + d + 64] + x1 * sinb[ci + d + 64];
  size_t di = (((size_t)b * nheads + h) * SEQ + s) * HD;
  u16 h1 = f2bf(o1), h2 = f2bf(o2);
  dhi[di + d] = h1;       dlo[di + d] = f2bf(o1 - bf2f(h1));
  dhi[di + d + 64] = h2;  dlo[di + d + 64] = f2bf(o2 - bf2f(h2));
}

// ---------------- V: (b,s,kv,d) f32 -> (b,kv,d,s) bf16 ----------------
__global__ void k_vt(const float* __restrict__ src, u16* __restrict__ dst){
  __shared__ float tile[32][33];
  int b = blockIdx.z >> 2, kv = blockIdx.z & 3;
  int s0 = blockIdx.x * 32, d0 = blockIdx.y * 32;
  int c = threadIdx.x & 31, r = threadIdx.x >> 5;
#pragma unroll
  for (int rr = 0; rr < 32; rr += 8)
    tile[r + rr][c] = src[(((size_t)b * SEQ + s0 + r + rr) * NKV + kv) * HD + d0 + c];
  __syncthreads();
#pragma unroll
  for (int rr = 0; rr < 32; rr += 8)
    dst[(((size_t)b * NKV + kv) * HD + d0 + r + rr) * SEQ + s0 + c] = f2bf(tile[c][r + rr]);
}

// ---------------- scores (flat lower-tri tile grid): raw scaled QK^T + per-tile partial m,l ----------------
__global__ __launch_bounds__(256, 4) void k_scores(
    const u16* __restrict__ qh, const u16* __restrict__ ql,
    const u16* __restrict__ kh, const u16* __restrict__ klo,
    float* __restrict__ wraw, float* __restrict__ pm, float* __restrict__ pl){
  int x = blockIdx.x;  // 0..135 -> (qt,kt), kt<=qt
  int qt = (int)((sqrtf(8.f * (float)x + 1.f) - 1.f) * 0.5f);
  while (qt * (qt + 1) / 2 > x) --qt;
  while ((qt + 1) * (qt + 2) / 2 <= x) ++qt;
  int kt = x - qt * (qt + 1) / 2;
  int h = blockIdx.y, b = blockIdx.z;
  int tid = threadIdx.x, lane = tid & 63, w = tid >> 6;
  int wm = w >> 1, wn = w & 1;
  int ml = lane & 15, kg = lane >> 4, kl8 = kg * 8;
  const u16* qbh = qh + ((size_t)b * NH + h) * SEQ * HD;
  const u16* qbl = ql + ((size_t)b * NH + h) * SEQ * HD;
  const u16* kbh = kh + ((size_t)b * NKV + h / GROUPS) * SEQ * HD;
  const u16* kbl = klo + ((size_t)b * NKV + h / GROUPS) * SEQ * HD;
  float* wout = wraw + ((size_t)b * NH + h) * SEQ * SEQ;

  f32x4 acc[4][4] = {};
#pragma unroll
  for (int ds = 0; ds < 4; ++ds){
    int kk = ds * 32 + kl8;
    bf16x8 bh[4], bl[4];
#pragma unroll
    for (int fn = 0; fn < 4; ++fn){
      size_t off = (size_t)(kt * 128 + wn * 64 + fn * 16 + ml) * HD + kk;
      bh[fn] = ldfrag(kbh + off);
      bl[fn] = ldfrag(kbl + off);
    }
#pragma unroll
    for (int fm = 0; fm < 4; ++fm){
      size_t off = (size_t)(qt * 128 + wm * 64 + fm * 16 + ml) * HD + kk;
      bf16x8 ah = ldfrag(qbh + off);
      bf16x8 al = ldfrag(qbl + off);
#pragma unroll
      for (int fn = 0; fn < 4; ++fn){
        acc[fm][fn] = mfma(al, bh[fn], acc[fm][fn]);
        acc[fm][fn] = mfma(ah, bl[fn], acc[fm][fn]);
        acc[fm][fn] = mfma(ah, bh[fn], acc[fm][fn]);
      }
    }
  }
  bool diag = (kt == qt);
  __shared__ float sm[2][128], sl[2][128];
#pragma unroll
  for (int fm = 0; fm < 4; ++fm){
#pragma unroll
    for (int r = 0; r < 4; ++r){
      int lr = wm * 64 + fm * 16 + kg * 4 + r;  // row within tile
      int rg = qt * 128 + lr;                   // global q row
      float sv[4];
#pragma unroll
      for (int fn = 0; fn < 4; ++fn){
        float s = acc[fm][fn][r] * SCALE;
        int cg = kt * 128 + wn * 64 + fn * 16 + ml;
        wout[(size_t)rg * SEQ + cg] = s;
        if (diag && cg > rg) s = -1e30f;
        sv[fn] = s;
      }
      float tm = fmaxf(fmaxf(sv[0], sv[1]), fmaxf(sv[2], sv[3]));
#pragma unroll
      for (int xm = 1; xm < 16; xm <<= 1) tm = fmaxf(tm, __shfl_xor(tm, xm, 64));
      float ps = __expf(sv[0] - tm) + __expf(sv[1] - tm) +
                 __expf(sv[2] - tm) + __expf(sv[3] - tm);
#pragma unroll
      for (int xm = 1; xm < 16; xm <<= 1) ps += __shfl_xor(ps, xm, 64);
      if (ml == 0){ sm[wn][lr] = tm; sl[wn][lr] = ps; }
    }
  }
  __syncthreads();
  if (tid < 128){
    float m0 = sm[0][tid], m1 = sm[1][tid];
    float mm = fmaxf(m0, m1);
    float ll = sl[0][tid] * __expf(m0 - mm) + sl[1][tid] * __expf(m1 - mm);
    size_t pidx = ((((size_t)b * NH + h) * 16 + qt) * 16 + kt) * 128 + tid;
    pm[pidx] = mm;
    pl[pidx] = ll;
  }
}

// ---------------- reduce per-tile partials -> per-row m, 1/l ----------------
__global__ void k_mlred(const float* __restrict__ pm, const float* __restrict__ pl,
                        float* __restrict__ mrow, float* __restrict__ lrinv){
  int idx = blockIdx.x * blockDim.x + threadIdx.x;  // B*NH*SEQ = 65536
  int row = idx & (SEQ - 1);
  int bh = idx >> 11;
  int qt = row >> 7, rt = row & 127;
  size_t base = (((size_t)bh * 16 + qt) * 16) * 128 + rt;
  float m = -1e30f;
  for (int kt = 0; kt <= qt; ++kt) m = fmaxf(m, pm[base + (size_t)kt * 128]);
  float l = 0.f;
  for (int kt = 0; kt <= qt; ++kt)
    l += pl[base + (size_t)kt * 128] * __expf(pm[base + (size_t)kt * 128] - m);
  mrow[(size_t)bh * SEQ + row] = m;
  lrinv[(size_t)bh * SEQ + row] = 1.0f / l;
}

// ---------------- zero-fill strictly-upper 64x64 tiles of weights ----------------
__global__ void k_zero(float* __restrict__ wmat){
  int x = blockIdx.x;  // 0..495 -> (k64,q64), q64 < k64
  int k = (int)((1.f + sqrtf(8.f * (float)x + 1.f)) * 0.5f);
  while (k * (k - 1) / 2 > x) --k;
  while ((k + 1) * k / 2 <= x) ++k;
  int q = x - k * (k - 1) / 2;
  int h = blockIdx.y, b = blockIdx.z;
  float* wb = wmat + ((size_t)b * NH + h) * SEQ * SEQ + (size_t)q * 64 * SEQ + k * 64;
  int r = threadIdx.x >> 2, c4 = threadIdx.x & 3;
  float4 z = make_float4(0.f, 0.f, 0.f, 0.f);
#pragma unroll
  for (int i = 0; i < 4; ++i)
    *reinterpret_cast<float4*>(wb + (size_t)r * SEQ + (c4 * 4 + i) * 4) = z;
}

// ---------------- PV fused with weight finalize (in-place raw->final) ----------------
// 64-row q-tiles, 4 waves x 16 rows, tiles paired (p, 31-p) for balance.
__global__ __launch_bounds__(256, 4) void k_pv(
    float* __restrict__ wbuf, const u16* __restrict__ vt, u16* __restrict__ ao,
    const float* __restrict__ mrow, const float* __restrict__ lrinv){
  int p = blockIdx.x, h = blockIdx.y, b = blockIdx.z;
  int tid = threadIdx.x, lane = tid & 63, w = tid >> 6;
  int ml = lane & 15, kg = lane >> 4;
  float* wb = wbuf + ((size_t)b * NH + h) * SEQ * SEQ;
  const u16* vb = vt + ((size_t)b * NKV + h / GROUPS) * HD * SEQ;
  const float* mr = mrow + (size_t)(b * NH + h) * SEQ;
  const float* lr = lrinv + (size_t)(b * NH + h) * SEQ;
#pragma unroll
  for (int half = 0; half < 2; ++half){
    int i = half ? (31 - p) : p;
    int rg = i * 64 + w * 16 + ml;  // this lane's P row
    float m = mr[rg], rl = lr[rg];
    f32x4 acc[8] = {};
    int nks = 2 * i + 2;
    for (int ks = 0; ks < nks; ++ks){
      int kb = ks * 32 + kg * 8;
      bf16x8 bfr[8];
#pragma unroll
      for (int fn = 0; fn < 8; ++fn)
        bfr[fn] = ldfrag(vb + (size_t)(fn * 16 + ml) * SEQ + kb);
      float* ap = wb + (size_t)rg * SEQ + kb;
      float4 s0 = *reinterpret_cast<const float4*>(ap);
      float4 s1 = *reinterpret_cast<const float4*>(ap + 4);
      float pe[8] = {s0.x, s0.y, s0.z, s0.w, s1.x, s1.y, s1.z, s1.w};
      union { bf16x8 v; u16 us[8]; } pk;
#pragma unroll
      for (int j = 0; j < 8; ++j){
        float e = (kb + j <= rg) ? __expf(pe[j] - m) * rl : 0.f;
        pe[j] = e;
        pk.us[j] = f2bf(e);
      }
      *reinterpret_cast<float4*>(ap) = make_float4(pe[0], pe[1], pe[2], pe[3]);
      *reinterpret_cast<float4*>(ap + 4) = make_float4(pe[4], pe[5], pe[6], pe[7]);
#pragma unroll
      for (int fn = 0; fn < 8; ++fn)
        acc[fn] = mfma(pk.v, bfr[fn], acc[fn]);
    }
#pragma unroll
    for (int fn = 0; fn < 8; ++fn)
#pragma unroll
      for (int r = 0; r < 4; ++r)
        ao[((size_t)b * SEQ + i * 64 + w * 16 + kg * 4 + r) * (NH * HD) + h * HD +
           fn * 16 + ml] = f2bf(acc[fn][r]);
  }
}

extern "C" void kernel_launch(void* const* d_in, const int* in_sizes, int n_in,
                              void* d_out, int out_size, void* d_ws, size_t ws_size,
                              hipStream_t stream){
  (void)in_sizes; (void)n_in; (void)out_size; (void)ws_size;
  const float* hs   = (const float*)d_in[0];
  const float* cosb = (const float*)d_in[1];
  const float* sinb = (const float*)d_in[2];
  // d_in[3] attention_mask unused: exactly the causal mask, applied analytically
  const float* Wq = (const float*)d_in[4];
  const float* Wk = (const float*)d_in[5];
  const float* Wv = (const float*)d_in[6];
  const float* Wo = (const float*)d_in[7];
  float* out  = (float*)d_out;
  float* wmat = out + (size_t)BATCH * SEQ * HIDDEN;  // attn_weights region

  char* ws = (char*)d_ws;
  size_t off = 0;
  auto alloc = [&](size_t bytes)->char*{
    char* p = ws + off; off += (bytes + 255) & ~(size_t)255; return p;
  };
  u16* hs_hi = (u16*)alloc(16777216);
  u16* hs_lo = (u16*)alloc(16777216);
  u16* wq_hi = (u16*)alloc(8388608);
  u16* wq_lo = (u16*)alloc(8388608);
  u16* wk_hi = (u16*)alloc(2097152);
  u16* wk_lo = (u16*)alloc(2097152);
  u16* wv_t  = (u16*)alloc(2097152);
  u16* wo_t  = (u16*)alloc(8388608);
  float* Qraw = (float*)alloc(33554432);
  float* Kraw = (float*)alloc(8388608);
  float* Vraw = (float*)alloc(8388608);
  u16* q_hi = (u16*)alloc(16777216);
  u16* q_lo = (u16*)alloc(16777216);
  u16* k_hi = (u16*)alloc(4194304);
  u16* k_lo = (u16*)alloc(4194304);
  u16* v_t  = (u16*)alloc(4194304);
  float* mrow = (float*)alloc(262144);
  float* lrow = (float*)alloc(262144);
  float* pm   = (float*)alloc(4194304);
  float* pl   = (float*)alloc(4194304);
  u16* ao = (u16*)Qraw;  // reuse: Qraw dead after k_rope(Q)

  size_t lds_split = 4 * 128 * 40 * sizeof(u16);
  size_t lds_plain = 2 * 128 * 40 * sizeof(u16);

  k_split<<<8192, 256, 0, stream>>>(hs, hs_hi, hs_lo, BATCH * SEQ * HIDDEN / 4);
  k_wt<true ><<<dim3(64, 64), 256, 0, stream>>>(Wq, wq_hi, wq_lo, HIDDEN, NH * HD);
  k_wt<true ><<<dim3(64, 16), 256, 0, stream>>>(Wk, wk_hi, wk_lo, HIDDEN, NKV * HD);
  k_wt<false><<<dim3(64, 16), 256, 0, stream>>>(Wv, wv_t, nullptr, HIDDEN, NKV * HD);
  k_wt<false><<<dim3(64, 64), 256, 0, stream>>>(Wo, wo_t, nullptr, NH * HD, HIDDEN);

  k_gemm<true ><<<dim3(32, 16), 256, lds_split, stream>>>(hs_hi, hs_lo, wq_hi, wq_lo, Qraw, 4096, 2048, 2048);
  k_gemm<true ><<<dim3(32,  4), 256, lds_split, stream>>>(hs_hi, hs_lo, wk_hi, wk_lo, Kraw, 4096,  512, 2048);
  k_gemm<false><<<dim3(32,  4), 256, lds_plain, stream>>>(hs_hi, nullptr, wv_t, nullptr, Vraw, 4096, 512, 2048);

  k_rope<<<BATCH * SEQ * NH  / 4, 256, 0, stream>>>(Qraw, cosb, sinb, q_hi, q_lo, NH);
  k_rope<<<BATCH * SEQ * NKV / 4, 256, 0, stream>>>(Kraw, cosb, sinb, k_hi, k_lo, NKV);
  k_vt<<<dim3(64, 4, 8), 256, 0, stream>>>(Vraw, v_t);

  k_scores<<<dim3(136, 16, 2), 256, 0, stream>>>(q_hi, q_lo, k_hi, k_lo, wmat, pm, pl);
  k_mlred<<<256, 256, 0, stream>>>(pm, pl, mrow, lrow);
  k_zero<<<dim3(496, 16, 2), 256, 0, stream>>>(wmat);
  k_pv<<<dim3(16, 16, 2), 256, 0, stream>>>(wmat, v_t, (u16*)ao, mrow, lrow);

  k_gemm<false><<<dim3(32, 16), 256, lds_plain, stream>>>(ao, nullptr, wo_t, nullptr, out, 4096, 2048, 2048);
}

// Round 3
// 1005.967 us; speedup vs baseline: 1.1323x; 1.0133x over previous
//
#include <hip/hip_runtime.h>
#include <hip/hip_bf16.h>
#include <math.h>

typedef unsigned short u16;
typedef __bf16 bf16_t;
typedef bf16_t bf16x8 __attribute__((ext_vector_type(8)));
typedef float f32x4 __attribute__((ext_vector_type(4)));

#define DEVI static __device__ __forceinline__

constexpr int BATCH = 2, SEQ = 2048, HIDDEN = 2048, NH = 16, NKV = 4, HD = 128;
constexpr int GROUPS = NH / NKV;
constexpr float SCALE = 0.08838834764831845f;  // 128^-0.5

DEVI u16 f2bf(float x){
  unsigned u = __float_as_uint(x);
  u += 0x7FFFu + ((u >> 16) & 1u);
  return (u16)(u >> 16);
}
DEVI float bf2f(u16 h){ return __uint_as_float(((unsigned)h) << 16); }

union FragU { uint4 u; bf16x8 b; };
DEVI bf16x8 ldfrag(const u16* p){
  FragU f; f.u = *reinterpret_cast<const uint4*>(p); return f.b;
}
DEVI f32x4 mfma(bf16x8 a, bf16x8 b, f32x4 c){
  return __builtin_amdgcn_mfma_f32_16x16x32_bf16(a, b, c, 0, 0, 0);
}

// async global->LDS, 16B per lane; lds base must be wave-uniform (lane x16 implicit)
DEVI void gll16(const u16* g, u16* lds_base){
  __builtin_amdgcn_global_load_lds(
      (const __attribute__((address_space(1))) unsigned int*)g,
      (__attribute__((address_space(3))) unsigned int*)lds_base, 16, 0, 0);
}

// ---------------- elementwise split of hidden_states ----------------
__global__ void k_split(const float* __restrict__ in, u16* __restrict__ hi,
                        u16* __restrict__ lo, int n4){
  int i = blockIdx.x * blockDim.x + threadIdx.x;
  if (i >= n4) return;
  float4 v = reinterpret_cast<const float4*>(in)[i];
  ushort4 h, l;
  h.x = f2bf(v.x); l.x = f2bf(v.x - bf2f(h.x));
  h.y = f2bf(v.y); l.y = f2bf(v.y - bf2f(h.y));
  h.z = f2bf(v.z); l.z = f2bf(v.z - bf2f(h.z));
  h.w = f2bf(v.w); l.w = f2bf(v.w - bf2f(h.w));
  reinterpret_cast<ushort4*>(hi)[i] = h;
  reinterpret_cast<ushort4*>(lo)[i] = l;
}

// ---------------- transpose (K,N)->(N,K) + split convert ----------------
template<bool SPLIT>
__global__ void k_wt(const float* __restrict__ W, u16* __restrict__ hi,
                     u16* __restrict__ lo, int K, int N){
  __shared__ float tile[32][33];
  int k0 = blockIdx.x * 32, n0 = blockIdx.y * 32;
  int c = threadIdx.x & 31, r = threadIdx.x >> 5;
#pragma unroll
  for (int rr = 0; rr < 32; rr += 8)
    tile[r + rr][c] = W[(size_t)(k0 + r + rr) * N + n0 + c];
  __syncthreads();
#pragma unroll
  for (int rr = 0; rr < 32; rr += 8){
    int n = n0 + r + rr, k = k0 + c;
    float x = tile[c][r + rr];
    u16 h = f2bf(x);
    hi[(size_t)n * K + k] = h;
    if (SPLIT) lo[(size_t)n * K + k] = f2bf(x - bf2f(h));
  }
}

// ---------------- GEMM (m97 structure): A (M,K), B (N,K) row-major, C (M,N) f32 ----------------
// LDS tiles [128][32] bf16 linear (8KB). Staged via global_load_lds width=16.
template<bool SPLIT>
__global__ __launch_bounds__(256, 2) void k_gemm(
    const u16* __restrict__ Ah, const u16* __restrict__ Al,
    const u16* __restrict__ Bh, const u16* __restrict__ Bl,
    float* __restrict__ C, int M, int N, int K){
  extern __shared__ u16 smem[];
  u16* sAh = smem;            // 4096 elems
  u16* sBh = sAh + 4096;
  u16* sAl = sBh + 4096;      // only if SPLIT
  u16* sBl = sAl + 4096;
  int tid = threadIdx.x, lane = tid & 63, w = tid >> 6;
  int wm = w >> 1, wn = w & 1;
  int ml = lane & 15, kg = lane >> 4, kl8 = kg * 8;
  int m0 = blockIdx.x * 128, n0 = blockIdx.y * 128;
  // per-lane global source offsets for staging: segment g = i*4+w, lane reads
  // row g*16 + (lane>>2), col (lane&3)*8 (16B)
  int srow = lane >> 2, scol = (lane & 3) * 8;
  f32x4 acc[4][4] = {};
  for (int k0 = 0; k0 < K; k0 += 32){
    __syncthreads();  // previous iter's reads done before overwrite
#pragma unroll
    for (int i = 0; i < 2; ++i){
      int g = i * 4 + w;
      size_t ga = (size_t)(g * 16 + srow) * K + k0 + scol;
      u16* lb = (u16*)(smem + g * 512);  // wave-uniform base within tile
      gll16(Ah + (size_t)m0 * K + ga, sAh + g * 512);
      gll16(Bh + (size_t)n0 * K + ga, sBh + g * 512);
      if (SPLIT){
        gll16(Al + (size_t)m0 * K + ga, sAl + g * 512);
        gll16(Bl + (size_t)n0 * K + ga, sBl + g * 512);
      }
      (void)lb;
    }
    __syncthreads();  // compiler drains vmcnt before barrier
    bf16x8 bh[4], bl[4];
#pragma unroll
    for (int fn = 0; fn < 4; ++fn){
      bh[fn] = ldfrag(sBh + (wn * 64 + fn * 16 + ml) * 32 + kl8);
      if (SPLIT) bl[fn] = ldfrag(sBl + (wn * 64 + fn * 16 + ml) * 32 + kl8);
    }
#pragma unroll
    for (int fm = 0; fm < 4; ++fm){
      bf16x8 ah = ldfrag(sAh + (wm * 64 + fm * 16 + ml) * 32 + kl8);
      bf16x8 al;
      if (SPLIT) al = ldfrag(sAl + (wm * 64 + fm * 16 + ml) * 32 + kl8);
#pragma unroll
      for (int fn = 0; fn < 4; ++fn){
        if (SPLIT){
          acc[fm][fn] = mfma(al, bh[fn], acc[fm][fn]);
          acc[fm][fn] = mfma(ah, bl[fn], acc[fm][fn]);
        }
        acc[fm][fn] = mfma(ah, bh[fn], acc[fm][fn]);
      }
    }
  }
#pragma unroll
  for (int fm = 0; fm < 4; ++fm)
#pragma unroll
    for (int fn = 0; fn < 4; ++fn)
#pragma unroll
      for (int r = 0; r < 4; ++r)
        C[(size_t)(m0 + wm * 64 + fm * 16 + kg * 4 + r) * N +
          n0 + wn * 64 + fn * 16 + ml] = acc[fm][fn][r];
}

// ---------------- RoPE + split + (b,s,h,d)->(b,h,s,d) ----------------
__global__ void k_rope(const float* __restrict__ src, const float* __restrict__ cosb,
                       const float* __restrict__ sinb, u16* __restrict__ dhi,
                       u16* __restrict__ dlo, int nheads){
  int row = blockIdx.x * 4 + (threadIdx.x >> 6);
  int d = threadIdx.x & 63;
  int h = row % nheads;
  int bs = row / nheads;
  int s = bs & (SEQ - 1);
  int b = bs >> 11;
  const float* sp = src + (size_t)row * HD;
  float x1 = sp[d], x2 = sp[d + 64];
  size_t ci = ((size_t)b * SEQ + s) * HD;
  float o1 = x1 * cosb[ci + d] - x2 * sinb[ci + d];
  float o2 = x2 * cosb[ci + d + 64] + x1 * sinb[ci + d + 64];
  size_t di = (((size_t)b * nheads + h) * SEQ + s) * HD;
  u16 h1 = f2bf(o1), h2 = f2bf(o2);
  dhi[di + d] = h1;       dlo[di + d] = f2bf(o1 - bf2f(h1));
  dhi[di + d + 64] = h2;  dlo[di + d + 64] = f2bf(o2 - bf2f(h2));
}

// ---------------- V: (b,s,kv,d) f32 -> (b,kv,d,s) bf16 ----------------
__global__ void k_vt(const float* __restrict__ src, u16* __restrict__ dst){
  __shared__ float tile[32][33];
  int b = blockIdx.z >> 2, kv = blockIdx.z & 3;
  int s0 = blockIdx.x * 32, d0 = blockIdx.y * 32;
  int c = threadIdx.x & 31, r = threadIdx.x >> 5;
#pragma unroll
  for (int rr = 0; rr < 32; rr += 8)
    tile[r + rr][c] = src[(((size_t)b * SEQ + s0 + r + rr) * NKV + kv) * HD + d0 + c];
  __syncthreads();
#pragma unroll
  for (int rr = 0; rr < 32; rr += 8)
    dst[(((size_t)b * NKV + kv) * HD + d0 + r + rr) * SEQ + s0 + c] = f2bf(tile[c][r + rr]);
}

// ---------------- scores (flat lower-tri tile grid): raw scaled QK^T + per-tile partial m,l ----------------
__global__ __launch_bounds__(256, 4) void k_scores(
    const u16* __restrict__ qh, const u16* __restrict__ ql,
    const u16* __restrict__ kh, const u16* __restrict__ klo,
    float* __restrict__ wraw, float* __restrict__ pm, float* __restrict__ pl){
  int x = blockIdx.x;  // 0..135 -> (qt,kt), kt<=qt
  int qt = (int)((sqrtf(8.f * (float)x + 1.f) - 1.f) * 0.5f);
  while (qt * (qt + 1) / 2 > x) --qt;
  while ((qt + 1) * (qt + 2) / 2 <= x) ++qt;
  int kt = x - qt * (qt + 1) / 2;
  int h = blockIdx.y, b = blockIdx.z;
  int tid = threadIdx.x, lane = tid & 63, w = tid >> 6;
  int wm = w >> 1, wn = w & 1;
  int ml = lane & 15, kg = lane >> 4, kl8 = kg * 8;
  const u16* qbh = qh + ((size_t)b * NH + h) * SEQ * HD;
  const u16* qbl = ql + ((size_t)b * NH + h) * SEQ * HD;
  const u16* kbh = kh + ((size_t)b * NKV + h / GROUPS) * SEQ * HD;
  const u16* kbl = klo + ((size_t)b * NKV + h / GROUPS) * SEQ * HD;
  float* wout = wraw + ((size_t)b * NH + h) * SEQ * SEQ;

  f32x4 acc[4][4] = {};
#pragma unroll
  for (int ds = 0; ds < 4; ++ds){
    int kk = ds * 32 + kl8;
    bf16x8 bh[4], bl[4];
#pragma unroll
    for (int fn = 0; fn < 4; ++fn){
      size_t off = (size_t)(kt * 128 + wn * 64 + fn * 16 + ml) * HD + kk;
      bh[fn] = ldfrag(kbh + off);
      bl[fn] = ldfrag(kbl + off);
    }
#pragma unroll
    for (int fm = 0; fm < 4; ++fm){
      size_t off = (size_t)(qt * 128 + wm * 64 + fm * 16 + ml) * HD + kk;
      bf16x8 ah = ldfrag(qbh + off);
      bf16x8 al = ldfrag(qbl + off);
#pragma unroll
      for (int fn = 0; fn < 4; ++fn){
        acc[fm][fn] = mfma(al, bh[fn], acc[fm][fn]);
        acc[fm][fn] = mfma(ah, bl[fn], acc[fm][fn]);
        acc[fm][fn] = mfma(ah, bh[fn], acc[fm][fn]);
      }
    }
  }
  bool diag = (kt == qt);
  __shared__ float sm[2][128], sl[2][128];
#pragma unroll
  for (int fm = 0; fm < 4; ++fm){
#pragma unroll
    for (int r = 0; r < 4; ++r){
      int lr = wm * 64 + fm * 16 + kg * 4 + r;  // row within tile
      int rg = qt * 128 + lr;                   // global q row
      float sv[4];
#pragma unroll
      for (int fn = 0; fn < 4; ++fn){
        float s = acc[fm][fn][r] * SCALE;
        int cg = kt * 128 + wn * 64 + fn * 16 + ml;
        wout[(size_t)rg * SEQ + cg] = s;
        if (diag && cg > rg) s = -1e30f;
        sv[fn] = s;
      }
      float tm = fmaxf(fmaxf(sv[0], sv[1]), fmaxf(sv[2], sv[3]));
#pragma unroll
      for (int xm = 1; xm < 16; xm <<= 1) tm = fmaxf(tm, __shfl_xor(tm, xm, 64));
      float ps = __expf(sv[0] - tm) + __expf(sv[1] - tm) +
                 __expf(sv[2] - tm) + __expf(sv[3] - tm);
#pragma unroll
      for (int xm = 1; xm < 16; xm <<= 1) ps += __shfl_xor(ps, xm, 64);
      if (ml == 0){ sm[wn][lr] = tm; sl[wn][lr] = ps; }
    }
  }
  __syncthreads();
  if (tid < 128){
    float m0 = sm[0][tid], m1 = sm[1][tid];
    float mm = fmaxf(m0, m1);
    float ll = sl[0][tid] * __expf(m0 - mm) + sl[1][tid] * __expf(m1 - mm);
    size_t pidx = ((((size_t)b * NH + h) * 16 + qt) * 16 + kt) * 128 + tid;
    pm[pidx] = mm;
    pl[pidx] = ll;
  }
}

// ---------------- reduce per-tile partials -> per-row m, 1/l ----------------
__global__ void k_mlred(const float* __restrict__ pm, const float* __restrict__ pl,
                        float* __restrict__ mrow, float* __restrict__ lrinv){
  int idx = blockIdx.x * blockDim.x + threadIdx.x;  // B*NH*SEQ = 65536
  int row = idx & (SEQ - 1);
  int bh = idx >> 11;
  int qt = row >> 7, rt = row & 127;
  size_t base = (((size_t)bh * 16 + qt) * 16) * 128 + rt;
  float m = -1e30f;
  for (int kt = 0; kt <= qt; ++kt) m = fmaxf(m, pm[base + (size_t)kt * 128]);
  float l = 0.f;
  for (int kt = 0; kt <= qt; ++kt)
    l += pl[base + (size_t)kt * 128] * __expf(pm[base + (size_t)kt * 128] - m);
  mrow[(size_t)bh * SEQ + row] = m;
  lrinv[(size_t)bh * SEQ + row] = 1.0f / l;
}

// ---------------- zero-fill strictly-upper 64x64 tiles of weights ----------------
__global__ void k_zero(float* __restrict__ wmat){
  int x = blockIdx.x;  // 0..495 -> (k64,q64), q64 < k64
  int k = (int)((1.f + sqrtf(8.f * (float)x + 1.f)) * 0.5f);
  while (k * (k - 1) / 2 > x) --k;
  while ((k + 1) * k / 2 <= x) ++k;
  int q = x - k * (k - 1) / 2;
  int h = blockIdx.y, b = blockIdx.z;
  float* wb = wmat + ((size_t)b * NH + h) * SEQ * SEQ + (size_t)q * 64 * SEQ + k * 64;
  int r = threadIdx.x >> 2, c4 = threadIdx.x & 3;
  float4 z = make_float4(0.f, 0.f, 0.f, 0.f);
#pragma unroll
  for (int i = 0; i < 4; ++i)
    *reinterpret_cast<float4*>(wb + (size_t)r * SEQ + (c4 * 4 + i) * 4) = z;
}

// ---------------- PV fused with weight finalize (in-place raw->final) ----------------
__global__ __launch_bounds__(256, 4) void k_pv(
    float* __restrict__ wbuf, const u16* __restrict__ vt, u16* __restrict__ ao,
    const float* __restrict__ mrow, const float* __restrict__ lrinv){
  int p = blockIdx.x, h = blockIdx.y, b = blockIdx.z;
  int tid = threadIdx.x, lane = tid & 63, w = tid >> 6;
  int ml = lane & 15, kg = lane >> 4;
  float* wb = wbuf + ((size_t)b * NH + h) * SEQ * SEQ;
  const u16* vb = vt + ((size_t)b * NKV + h / GROUPS) * HD * SEQ;
  const float* mr = mrow + (size_t)(b * NH + h) * SEQ;
  const float* lr = lrinv + (size_t)(b * NH + h) * SEQ;
#pragma unroll
  for (int half = 0; half < 2; ++half){
    int i = half ? (31 - p) : p;
    int rg = i * 64 + w * 16 + ml;  // this lane's P row
    float m = mr[rg], rl = lr[rg];
    f32x4 acc[8] = {};
    int nks = 2 * i + 2;
    for (int ks = 0; ks < nks; ++ks){
      int kb = ks * 32 + kg * 8;
      bf16x8 bfr[8];
#pragma unroll
      for (int fn = 0; fn < 8; ++fn)
        bfr[fn] = ldfrag(vb + (size_t)(fn * 16 + ml) * SEQ + kb);
      float* ap = wb + (size_t)rg * SEQ + kb;
      float4 s0 = *reinterpret_cast<const float4*>(ap);
      float4 s1 = *reinterpret_cast<const float4*>(ap + 4);
      float pe[8] = {s0.x, s0.y, s0.z, s0.w, s1.x, s1.y, s1.z, s1.w};
      union { bf16x8 v; u16 us[8]; } pk;
#pragma unroll
      for (int j = 0; j < 8; ++j){
        float e = (kb + j <= rg) ? __expf(pe[j] - m) * rl : 0.f;
        pe[j] = e;
        pk.us[j] = f2bf(e);
      }
      *reinterpret_cast<float4*>(ap) = make_float4(pe[0], pe[1], pe[2], pe[3]);
      *reinterpret_cast<float4*>(ap + 4) = make_float4(pe[4], pe[5], pe[6], pe[7]);
#pragma unroll
      for (int fn = 0; fn < 8; ++fn)
        acc[fn] = mfma(pk.v, bfr[fn], acc[fn]);
    }
#pragma unroll
    for (int fn = 0; fn < 8; ++fn)
#pragma unroll
      for (int r = 0; r < 4; ++r)
        ao[((size_t)b * SEQ + i * 64 + w * 16 + kg * 4 + r) * (NH * HD) + h * HD +
           fn * 16 + ml] = f2bf(acc[fn][r]);
  }
}

extern "C" void kernel_launch(void* const* d_in, const int* in_sizes, int n_in,
                              void* d_out, int out_size, void* d_ws, size_t ws_size,
                              hipStream_t stream){
  (void)in_sizes; (void)n_in; (void)out_size; (void)ws_size;
  const float* hs   = (const float*)d_in[0];
  const float* cosb = (const float*)d_in[1];
  const float* sinb = (const float*)d_in[2];
  // d_in[3] attention_mask unused: exactly the causal mask, applied analytically
  const float* Wq = (const float*)d_in[4];
  const float* Wk = (const float*)d_in[5];
  const float* Wv = (const float*)d_in[6];
  const float* Wo = (const float*)d_in[7];
  float* out  = (float*)d_out;
  float* wmat = out + (size_t)BATCH * SEQ * HIDDEN;  // attn_weights region

  char* ws = (char*)d_ws;
  size_t off = 0;
  auto alloc = [&](size_t bytes)->char*{
    char* p = ws + off; off += (bytes + 255) & ~(size_t)255; return p;
  };
  u16* hs_hi = (u16*)alloc(16777216);
  u16* hs_lo = (u16*)alloc(16777216);
  u16* wq_hi = (u16*)alloc(8388608);
  u16* wq_lo = (u16*)alloc(8388608);
  u16* wk_hi = (u16*)alloc(2097152);
  u16* wk_lo = (u16*)alloc(2097152);
  u16* wv_t  = (u16*)alloc(2097152);
  u16* wo_t  = (u16*)alloc(8388608);
  float* Qraw = (float*)alloc(33554432);
  float* Kraw = (float*)alloc(8388608);
  float* Vraw = (float*)alloc(8388608);
  u16* q_hi = (u16*)alloc(16777216);
  u16* q_lo = (u16*)alloc(16777216);
  u16* k_hi = (u16*)alloc(4194304);
  u16* k_lo = (u16*)alloc(4194304);
  u16* v_t  = (u16*)alloc(4194304);
  float* mrow = (float*)alloc(262144);
  float* lrow = (float*)alloc(262144);
  float* pm   = (float*)alloc(4194304);
  float* pl   = (float*)alloc(4194304);
  u16* ao = (u16*)Qraw;  // reuse: Qraw dead after k_rope(Q)

  size_t lds_split = 4 * 4096 * sizeof(u16);   // 32 KB
  size_t lds_plain = 2 * 4096 * sizeof(u16);   // 16 KB

  k_split<<<8192, 256, 0, stream>>>(hs, hs_hi, hs_lo, BATCH * SEQ * HIDDEN / 4);
  k_wt<true ><<<dim3(64, 64), 256, 0, stream>>>(Wq, wq_hi, wq_lo, HIDDEN, NH * HD);
  k_wt<true ><<<dim3(64, 16), 256, 0, stream>>>(Wk, wk_hi, wk_lo, HIDDEN, NKV * HD);
  k_wt<false><<<dim3(64, 16), 256, 0, stream>>>(Wv, wv_t, nullptr, HIDDEN, NKV * HD);
  k_wt<false><<<dim3(64, 64), 256, 0, stream>>>(Wo, wo_t, nullptr, NH * HD, HIDDEN);

  k_gemm<true ><<<dim3(32, 16), 256, lds_split, stream>>>(hs_hi, hs_lo, wq_hi, wq_lo, Qraw, 4096, 2048, 2048);
  k_gemm<true ><<<dim3(32,  4), 256, lds_split, stream>>>(hs_hi, hs_lo, wk_hi, wk_lo, Kraw, 4096,  512, 2048);
  k_gemm<false><<<dim3(32,  4), 256, lds_plain, stream>>>(hs_hi, nullptr, wv_t, nullptr, Vraw, 4096, 512, 2048);

  k_rope<<<BATCH * SEQ * NH  / 4, 256, 0, stream>>>(Qraw, cosb, sinb, q_hi, q_lo, NH);
  k_rope<<<BATCH * SEQ * NKV / 4, 256, 0, stream>>>(Kraw, cosb, sinb, k_hi, k_lo, NKV);
  k_vt<<<dim3(64, 4, 8), 256, 0, stream>>>(Vraw, v_t);

  k_scores<<<dim3(136, 16, 2), 256, 0, stream>>>(q_hi, q_lo, k_hi, k_lo, wmat, pm, pl);
  k_mlred<<<256, 256, 0, stream>>>(pm, pl, mrow, lrow);
  k_zero<<<dim3(496, 16, 2), 256, 0, stream>>>(wmat);
  k_pv<<<dim3(16, 16, 2), 256, 0, stream>>>(wmat, v_t, (u16*)ao, mrow, lrow);

  k_gemm<false><<<dim3(32, 16), 256, lds_plain, stream>>>(ao, nullptr, wo_t, nullptr, out, 4096, 2048, 2048);
}